// Round 1
// baseline (443.632 us; speedup 1.0000x reference)
//
#include <hip/hip_runtime.h>
#include <math.h>

namespace {
constexpr int B_   = 8;
constexpr int DIM_ = 2048;
constexpr int H_   = 16;
constexpr int QLR_ = 1536;
constexpr int KVLR_= 512;
constexpr int DN_  = 128;
constexpr int DR_  = 64;
constexpr int DV_  = 128;
constexpr int TPRE_= 8191;
constexpr int CE_  = 576;    // KVLR + DR
constexpr int NCH_ = 64;     // chunks over T=8192
constexpr int CT_  = 128;    // t per chunk
constexpr float EPS_ = 1e-6f;
constexpr float SCALE_ = 0.07216878364870322f; // (DN+DR)^-0.5
constexpr int SSTR_ = 20;    // padded LDS stride for score tile [128][20]

// workspace layout (float offsets)
constexpr size_t WS_QLAT  = 0;
constexpr size_t WS_KVPE  = WS_QLAT  + (size_t)B_*QLR_;
constexpr size_t WS_KVNEW = WS_KVPE  + (size_t)B_*CE_;
constexpr size_t WS_PENEW = WS_KVNEW + (size_t)B_*KVLR_;
constexpr size_t WS_QRS   = WS_PENEW + (size_t)B_*DR_;
constexpr size_t WS_QNOPE = WS_QRS   + (size_t)B_;
constexpr size_t WS_QT    = WS_QNOPE + (size_t)B_*H_*DN_;   // [b][576][16]
constexpr size_t WS_MLOC  = WS_QT    + (size_t)B_*CE_*H_;
constexpr size_t WS_LLOC  = WS_MLOC  + (size_t)B_*H_*NCH_;
constexpr size_t WS_OUT2  = WS_LLOC  + (size_t)B_*H_*NCH_;
constexpr size_t WS_OPART = WS_OUT2  + (size_t)B_*DIM_;     // [b][h][chunk][512]
} // namespace

// ---------------- K1: q_latent = x@wq_a^T + b ; kvpe = x@wkv_a^T + b ----------------
__global__ __launch_bounds__(256) void mla_k1(const float* __restrict__ x,
                                              const float* __restrict__ wqa,
                                              const float* __restrict__ bqa,
                                              const float* __restrict__ wkva,
                                              const float* __restrict__ bkva,
                                              float* __restrict__ ws) {
  const int w = threadIdx.x >> 6, l = threadIdx.x & 63;
  const int r = blockIdx.x * 4 + w;  // 0..2111
  const float* W; const float* bias; float* out; int rr; int ostride;
  if (r < QLR_) { W = wqa;  bias = bqa;  out = ws + WS_QLAT; rr = r;        ostride = QLR_; }
  else          { W = wkva; bias = bkva; out = ws + WS_KVPE; rr = r - QLR_; ostride = CE_;  }
  const float4* wp = (const float4*)(W + (size_t)rr * DIM_);
  const float4* x4 = (const float4*)x;
  float4 wv[8];
#pragma unroll
  for (int j = 0; j < 8; ++j) wv[j] = wp[l + 64 * j];
  float acc[B_];
#pragma unroll
  for (int b = 0; b < B_; ++b) acc[b] = 0.f;
#pragma unroll
  for (int b = 0; b < B_; ++b) {
#pragma unroll
    for (int j = 0; j < 8; ++j) {
      const float4 xv = x4[b * (DIM_ / 4) + l + 64 * j];
      acc[b] = fmaf(wv[j].x, xv.x, fmaf(wv[j].y, xv.y, fmaf(wv[j].z, xv.z, fmaf(wv[j].w, xv.w, acc[b]))));
    }
  }
#pragma unroll
  for (int b = 0; b < B_; ++b)
#pragma unroll
    for (int s = 32; s; s >>= 1) acc[b] += __shfl_xor(acc[b], s);
  if (l == 0) {
    const float b0 = bias[rr];
#pragma unroll
    for (int b = 0; b < B_; ++b) out[b * ostride + rr] = acc[b] + b0;
  }
}

// ---------------- K2: kv rms-norm + k_pe rope + q rms scales ----------------
__global__ __launch_bounds__(256) void mla_k2(const float* __restrict__ kvnw,
                                              const float* __restrict__ fcos,
                                              const float* __restrict__ fsin,
                                              float* __restrict__ ws) {
  const int tid = threadIdx.x;
  const int b = tid >> 5, i = tid & 31;
  const float* kvpe = ws + WS_KVPE + b * CE_;
  float ss = 0.f;
#pragma unroll
  for (int j = 0; j < KVLR_ / 32; ++j) { const float v = kvpe[i + 32 * j]; ss = fmaf(v, v, ss); }
#pragma unroll
  for (int s = 16; s; s >>= 1) ss += __shfl_xor(ss, s, 32);
  const float scale = 1.0f / sqrtf(ss / (float)KVLR_ + EPS_);
  float* kvn = ws + WS_KVNEW + b * KVLR_;
#pragma unroll
  for (int j = 0; j < KVLR_ / 32; ++j) {
    const int c = i + 32 * j;
    kvn[c] = kvpe[c] * kvnw[c] * scale;
  }
  { // rope new k_pe
    const float xr = kvpe[KVLR_ + 2 * i], xi = kvpe[KVLR_ + 2 * i + 1];
    const float c = fcos[i], s = fsin[i];
    float* pen = ws + WS_PENEW + b * DR_;
    pen[2 * i]     = xr * c - xi * s;
    pen[2 * i + 1] = xr * s + xi * c;
  }
  { // q latent rms scale per batch
    const float* p = ws + WS_QLAT + b * QLR_;
    float sq = 0.f;
#pragma unroll
    for (int j = 0; j < QLR_ / 32; ++j) { const float v = p[i + 32 * j]; sq = fmaf(v, v, sq); }
#pragma unroll
    for (int s = 16; s; s >>= 1) sq += __shfl_xor(sq, s, 32);
    if (i == 0) ws[WS_QRS + b] = 1.0f / sqrtf(sq / (float)QLR_ + EPS_);
  }
}

// ---------------- K3: q = rms(q_lat)*g @ wq_b^T + b ; split nope / rope(pe) ----------------
__global__ __launch_bounds__(256) void mla_k3(const float* __restrict__ qnw,
                                              const float* __restrict__ wqb,
                                              const float* __restrict__ bqb,
                                              const float* __restrict__ fcos,
                                              const float* __restrict__ fsin,
                                              float* __restrict__ ws) {
  const int w = threadIdx.x >> 6, l = threadIdx.x & 63;
  const int r0 = blockIdx.x * 8 + w * 2;  // 0..3070
  const float4* w0p = (const float4*)(wqb + (size_t)r0 * QLR_);
  const float4* w1p = (const float4*)(wqb + (size_t)(r0 + 1) * QLR_);
  const float4* g4  = (const float4*)qnw;
  const float4* x4  = (const float4*)(ws + WS_QLAT);
  float4 wg0[6], wg1[6];
#pragma unroll
  for (int j = 0; j < 6; ++j) {
    const int c4 = l + 64 * j;
    const float4 a = w0p[c4], bb = w1p[c4], g = g4[c4];
    wg0[j].x = a.x * g.x; wg0[j].y = a.y * g.y; wg0[j].z = a.z * g.z; wg0[j].w = a.w * g.w;
    wg1[j].x = bb.x * g.x; wg1[j].y = bb.y * g.y; wg1[j].z = bb.z * g.z; wg1[j].w = bb.w * g.w;
  }
  float acc0[B_], acc1[B_];
#pragma unroll
  for (int b = 0; b < B_; ++b) { acc0[b] = 0.f; acc1[b] = 0.f; }
#pragma unroll
  for (int b = 0; b < B_; ++b) {
#pragma unroll
    for (int j = 0; j < 6; ++j) {
      const float4 xv = x4[b * (QLR_ / 4) + l + 64 * j];
      acc0[b] = fmaf(wg0[j].x, xv.x, fmaf(wg0[j].y, xv.y, fmaf(wg0[j].z, xv.z, fmaf(wg0[j].w, xv.w, acc0[b]))));
      acc1[b] = fmaf(wg1[j].x, xv.x, fmaf(wg1[j].y, xv.y, fmaf(wg1[j].z, xv.z, fmaf(wg1[j].w, xv.w, acc1[b]))));
    }
  }
#pragma unroll
  for (int b = 0; b < B_; ++b)
#pragma unroll
    for (int s = 32; s; s >>= 1) {
      acc0[b] += __shfl_xor(acc0[b], s);
      acc1[b] += __shfl_xor(acc1[b], s);
    }
  if (l == 0) {
    const int h = r0 / (DN_ + DR_);
    const int j0 = r0 - h * (DN_ + DR_);
    const float b0 = bqb[r0], b1 = bqb[r0 + 1];
    if (j0 < DN_) {
      float* qn = ws + WS_QNOPE;
#pragma unroll
      for (int b = 0; b < B_; ++b) {
        const float sb = ws[WS_QRS + b];
        qn[(b * H_ + h) * DN_ + j0]     = acc0[b] * sb + b0;
        qn[(b * H_ + h) * DN_ + j0 + 1] = acc1[b] * sb + b1;
      }
    } else {
      const int i = (j0 - DN_) >> 1;
      const float c = fcos[i], s = fsin[i];
      float* qT = ws + WS_QT;
#pragma unroll
      for (int b = 0; b < B_; ++b) {
        const float sb = ws[WS_QRS + b];
        const float xr = acc0[b] * sb + b0, xi = acc1[b] * sb + b1;
        qT[((size_t)b * CE_ + KVLR_ + 2 * i) * H_ + h]     = xr * c - xi * s;
        qT[((size_t)b * CE_ + KVLR_ + 2 * i + 1) * H_ + h] = xr * s + xi * c;
      }
    }
  }
}

// ---------------- K4: q_abs[b][c][h] = sum_d q_nope[b][h][d] * wkv_b[h][d][c] ----------------
__global__ __launch_bounds__(256) void mla_k4(const float* __restrict__ wkvb,
                                              float* __restrict__ ws) {
  __shared__ float red[7 * 32 * B_];
  const int h = blockIdx.y;
  const int strip = blockIdx.x;
  const int tid = threadIdx.x;
  const int c = tid & 31, dg = tid >> 5;
  const int cg = strip * 32 + c;
  const float* qn = ws + WS_QNOPE;
  float acc[B_];
#pragma unroll
  for (int b = 0; b < B_; ++b) acc[b] = 0.f;
  const float* wp = wkvb + (size_t)h * 256 * KVLR_ + cg;
#pragma unroll
  for (int dd = 0; dd < 16; ++dd) {
    const int d = dg * 16 + dd;
    const float wv = wp[(size_t)d * KVLR_];
#pragma unroll
    for (int b = 0; b < B_; ++b) acc[b] = fmaf(qn[(b * H_ + h) * DN_ + d], wv, acc[b]);
  }
  if (dg > 0) {
#pragma unroll
    for (int b = 0; b < B_; ++b) red[(((dg - 1) * 32) + c) * B_ + b] = acc[b];
  }
  __syncthreads();
  if (dg == 0) {
    float* qT = ws + WS_QT;
#pragma unroll
    for (int b = 0; b < B_; ++b) {
      float v = acc[b];
#pragma unroll
      for (int g = 0; g < 7; ++g) v += red[(g * 32 + c) * B_ + b];
      qT[((size_t)b * CE_ + cg) * H_ + h] = v;
    }
  }
}

// ---------------- K5: flash-decode partials per (b, chunk) ----------------
// 512 threads (8 waves), CT=128. Phase A: wave-pair <-> t-half, 4-way dim split
// (quarters of the 576-dim dot product) -> 4x outstanding loads per kv row and
// 2 blocks/CU (50% occupancy) vs the old 1 block/CU at 12.5%.
__global__ __launch_bounds__(512, 4) void mla_k5(const float* __restrict__ kvpre,
                                                 const float* __restrict__ pepre,
                                                 float* __restrict__ ws) {
  __shared__ float part[4 * CT_ * SSTR_]; // 40 KB quarter partials [q][t][20]
  __shared__ float sl[CT_ * SSTR_];       // 10 KB scores -> p
  const int b = blockIdx.y;
  const int chunk = blockIdx.x;
  const int t0 = chunk * CT_;
  const int tid = threadIdx.x;
  const int w = tid >> 6, l = tid & 63;
  const float* kvnew = ws + WS_KVNEW;
  const float* penew = ws + WS_PENEW;

  // ---- phase A: score partials ----
  {
    const int q4 = w >> 1;                 // dim quarter 0..3
    const int tl = ((w & 1) << 6) + l;     // local t 0..127
    const int t = t0 + tl;
    const float* kvrow; const float* perow;
    if (t < TPRE_) {
      kvrow = kvpre + ((size_t)b * TPRE_ + t) * KVLR_;
      perow = pepre + ((size_t)b * TPRE_ + t) * DR_;
    } else {
      kvrow = kvnew + b * KVLR_;
      perow = penew + b * DR_;
    }
    const float* qTb = ws + WS_QT + (size_t)b * CE_ * H_;
    float acc[H_];
#pragma unroll
    for (int h = 0; h < H_; ++h) acc[h] = 0.f;
    auto fma4 = [&](const float4 k, const float* qc) {
#pragma unroll
      for (int h = 0; h < H_; ++h) {
        acc[h] = fmaf(qc[h],          k.x, acc[h]);
        acc[h] = fmaf(qc[H_ + h],     k.y, acc[h]);
        acc[h] = fmaf(qc[2 * H_ + h], k.z, acc[h]);
        acc[h] = fmaf(qc[3 * H_ + h], k.w, acc[h]);
      }
    };
    if (q4 < 3) {                           // kv dims [144*q4, 144*q4+144)
      const int cbase = q4 * 144;
#pragma unroll
      for (int c16 = 0; c16 < 144; c16 += 16) {
        const float4 k0 = *(const float4*)(kvrow + cbase + c16);
        const float4 k1 = *(const float4*)(kvrow + cbase + c16 + 4);
        const float4 k2 = *(const float4*)(kvrow + cbase + c16 + 8);
        const float4 k3 = *(const float4*)(kvrow + cbase + c16 + 12);
        const float* qc = qTb + (size_t)(cbase + c16) * H_;
        fma4(k0, qc);
        fma4(k1, qc + 4 * H_);
        fma4(k2, qc + 8 * H_);
        fma4(k3, qc + 12 * H_);
      }
    } else {                                // kv tail [432,512) + pe [0,64)
#pragma unroll
      for (int c16 = 432; c16 < 512; c16 += 16) {
        const float4 k0 = *(const float4*)(kvrow + c16);
        const float4 k1 = *(const float4*)(kvrow + c16 + 4);
        const float4 k2 = *(const float4*)(kvrow + c16 + 8);
        const float4 k3 = *(const float4*)(kvrow + c16 + 12);
        const float* qc = qTb + (size_t)c16 * H_;
        fma4(k0, qc);
        fma4(k1, qc + 4 * H_);
        fma4(k2, qc + 8 * H_);
        fma4(k3, qc + 12 * H_);
      }
#pragma unroll
      for (int c16 = 0; c16 < 64; c16 += 16) {
        const float4 k0 = *(const float4*)(perow + c16);
        const float4 k1 = *(const float4*)(perow + c16 + 4);
        const float4 k2 = *(const float4*)(perow + c16 + 8);
        const float4 k3 = *(const float4*)(perow + c16 + 12);
        const float* qc = qTb + (size_t)(KVLR_ + c16) * H_;
        fma4(k0, qc);
        fma4(k1, qc + 4 * H_);
        fma4(k2, qc + 8 * H_);
        fma4(k3, qc + 12 * H_);
      }
    }
    float* pp = part + (size_t)(q4 * CT_ + tl) * SSTR_;
#pragma unroll
    for (int g = 0; g < 4; ++g) {
      float4 v;
      v.x = acc[4 * g]; v.y = acc[4 * g + 1];
      v.z = acc[4 * g + 2]; v.w = acc[4 * g + 3];
      *(float4*)(pp + 4 * g) = v;
    }
  }
  __syncthreads();

  // ---- reduce quarter partials -> scaled scores ----
  {
#pragma unroll
    for (int k = 0; k < (CT_ * H_) / 512; ++k) {   // 4
      const int idx = tid + 512 * k;
      const int t = idx >> 4, h = idx & 15;
      const float v = part[(0 * CT_ + t) * SSTR_ + h]
                    + part[(1 * CT_ + t) * SSTR_ + h]
                    + part[(2 * CT_ + t) * SSTR_ + h]
                    + part[(3 * CT_ + t) * SSTR_ + h];
      sl[t * SSTR_ + h] = v * SCALE_;
    }
  }
  __syncthreads();

  // ---- phase B: chunk-local softmax per head (32 threads per head) ----
  {
    const int h2 = tid >> 5, grp = tid & 31;
    float m = -3.4e38f;
#pragma unroll
    for (int j = 0; j < CT_ / 32; ++j) m = fmaxf(m, sl[(grp + 32 * j) * SSTR_ + h2]);
#pragma unroll
    for (int s = 16; s; s >>= 1) m = fmaxf(m, __shfl_xor(m, s, 32));
    float lsum = 0.f;
#pragma unroll
    for (int j = 0; j < CT_ / 32; ++j) {
      const int idx = (grp + 32 * j) * SSTR_ + h2;
      const float p = __expf(sl[idx] - m);
      sl[idx] = p;
      lsum += p;
    }
#pragma unroll
    for (int s = 16; s; s >>= 1) lsum += __shfl_xor(lsum, s, 32);
    if (grp == 0) {
      ws[WS_MLOC + (b * H_ + h2) * NCH_ + chunk] = m;
      ws[WS_LLOC + (b * H_ + h2) * NCH_ + chunk] = lsum;
    }
  }
  __syncthreads();

  // ---- phase C: O_partial = sum_t p * kv  (wave <-> 2 heads, lanes <-> c) ----
  {
    float o[2][8];
#pragma unroll
    for (int a = 0; a < 2; ++a)
#pragma unroll
      for (int j = 0; j < 8; ++j) o[a][j] = 0.f;
    const int hb = w * 2;
    const float* kvb = kvpre + (size_t)b * TPRE_ * KVLR_;
    auto step = [&](const float* kr, int t) {
      const float2 p = *(const float2*)(sl + t * SSTR_ + hb);
#pragma unroll
      for (int j = 0; j < 4; ++j) {
        const float2 kv = *(const float2*)(kr + j * 128 + 2 * l);
        o[0][2 * j]     = fmaf(p.x, kv.x, o[0][2 * j]);
        o[0][2 * j + 1] = fmaf(p.x, kv.y, o[0][2 * j + 1]);
        o[1][2 * j]     = fmaf(p.y, kv.x, o[1][2 * j]);
        o[1][2 * j + 1] = fmaf(p.y, kv.y, o[1][2 * j + 1]);
      }
    };
    if (t0 + CT_ <= TPRE_) {
#pragma unroll 4
      for (int t = 0; t < CT_; ++t) step(kvb + (size_t)(t0 + t) * KVLR_, t);
    } else {
      const float* kvn = kvnew + b * KVLR_;
      for (int t = 0; t < CT_; ++t) {
        const float* kr = (t0 + t < TPRE_) ? (kvb + (size_t)(t0 + t) * KVLR_) : kvn;
        step(kr, t);
      }
    }
    float* Op = ws + WS_OPART;
#pragma unroll
    for (int a = 0; a < 2; ++a) {
#pragma unroll
      for (int j = 0; j < 4; ++j) {
        float2 v; v.x = o[a][2 * j]; v.y = o[a][2 * j + 1];
        *(float2*)(Op + (((size_t)(b * H_ + hb + a) * NCH_ + chunk) * KVLR_) + j * 128 + 2 * l) = v;
      }
    }
  }
}

// ---------------- K6: combine partials + project through wkv_b[:,128:,:] ----------------
__global__ __launch_bounds__(256) void mla_k6(const float* __restrict__ wkvb,
                                              float* __restrict__ ws) {
  const int h = blockIdx.x, b = blockIdx.y;
  __shared__ float wgt[NCH_];
  __shared__ float ao[KVLR_];
  __shared__ float Linv;
  const int tid = threadIdx.x;
  if (tid < NCH_) {   // NCH_=64: one full wave does the combine weights
    const float m = ws[WS_MLOC + (b * H_ + h) * NCH_ + tid];
    float M = m;
#pragma unroll
    for (int s = 32; s; s >>= 1) M = fmaxf(M, __shfl_xor(M, s));
    const float wv = __expf(m - M);
    wgt[tid] = wv;
    float lv = ws[WS_LLOC + (b * H_ + h) * NCH_ + tid] * wv;
#pragma unroll
    for (int s = 32; s; s >>= 1) lv += __shfl_xor(lv, s);
    if (tid == 0) Linv = 1.0f / lv;
  }
  __syncthreads();
  const float* Ob = ws + WS_OPART + (size_t)(b * H_ + h) * NCH_ * KVLR_;
  float s0 = 0.f, s1 = 0.f;
#pragma unroll 4
  for (int i = 0; i < NCH_; ++i) {
    const float wv = wgt[i];
    s0 = fmaf(wv, Ob[(size_t)i * KVLR_ + tid], s0);
    s1 = fmaf(wv, Ob[(size_t)i * KVLR_ + tid + 256], s1);
  }
  const float li = Linv;
  ao[tid] = s0 * li;
  ao[tid + 256] = s1 * li;
  __syncthreads();
  const int v = tid >> 1, half = tid & 1;
  const float* w2 = wkvb + ((size_t)h * 256 + DN_ + v) * KVLR_ + half * 256;
  const float* a = ao + half * 256;
  float s = 0.f;
#pragma unroll
  for (int c = 0; c < 256; c += 4) {
    const float4 wv = *(const float4*)(w2 + c);
    s = fmaf(wv.x, a[c], s);
    s = fmaf(wv.y, a[c + 1], s);
    s = fmaf(wv.z, a[c + 2], s);
    s = fmaf(wv.w, a[c + 3], s);
  }
  s += __shfl_xor(s, 1);
  if (half == 0) ws[WS_OUT2 + b * DIM_ + h * DV_ + v] = s;
}

// ---------------- K7: y = out2 @ wo^T + wo_b ----------------
__global__ __launch_bounds__(256) void mla_k7(const float* __restrict__ wo,
                                              const float* __restrict__ wob,
                                              const float* __restrict__ ws,
                                              float* __restrict__ out) {
  const int w = threadIdx.x >> 6, l = threadIdx.x & 63;
  const int r = blockIdx.x * 4 + w;  // 0..2047
  const float4* wp = (const float4*)(wo + (size_t)r * DIM_);
  const float4* x4 = (const float4*)(ws + WS_OUT2);
  float4 wv[8];
#pragma unroll
  for (int j = 0; j < 8; ++j) wv[j] = wp[l + 64 * j];
  float acc[B_];
#pragma unroll
  for (int b = 0; b < B_; ++b) acc[b] = 0.f;
#pragma unroll
  for (int b = 0; b < B_; ++b) {
#pragma unroll
    for (int j = 0; j < 8; ++j) {
      const float4 xv = x4[b * (DIM_ / 4) + l + 64 * j];
      acc[b] = fmaf(wv[j].x, xv.x, fmaf(wv[j].y, xv.y, fmaf(wv[j].z, xv.z, fmaf(wv[j].w, xv.w, acc[b]))));
    }
  }
#pragma unroll
  for (int b = 0; b < B_; ++b)
#pragma unroll
    for (int s = 32; s; s >>= 1) acc[b] += __shfl_xor(acc[b], s);
  if (l == 0) {
    const float b0 = wob[r];
#pragma unroll
    for (int b = 0; b < B_; ++b) out[b * DIM_ + r] = acc[b] + b0;
  }
}

extern "C" void kernel_launch(void* const* d_in, const int* in_sizes, int n_in,
                              void* d_out, int out_size, void* d_ws, size_t ws_size,
                              hipStream_t stream) {
  (void)in_sizes; (void)n_in; (void)out_size; (void)ws_size;
  const float* x     = (const float*)d_in[0];
  const float* fcos  = (const float*)d_in[2];
  const float* fsin  = (const float*)d_in[3];
  const float* kvpre = (const float*)d_in[4];
  const float* pepre = (const float*)d_in[5];
  const float* wqa   = (const float*)d_in[6];
  const float* bqa   = (const float*)d_in[7];
  const float* qnw   = (const float*)d_in[8];
  const float* wqb   = (const float*)d_in[9];
  const float* bqb   = (const float*)d_in[10];
  const float* wkva  = (const float*)d_in[11];
  const float* bkva  = (const float*)d_in[12];
  const float* kvnw  = (const float*)d_in[13];
  const float* wkvb  = (const float*)d_in[14];
  const float* wo    = (const float*)d_in[15];
  const float* wob   = (const float*)d_in[16];
  float* ws  = (float*)d_ws;
  float* out = (float*)d_out;

  mla_k1<<<dim3((QLR_ + CE_) / 4), dim3(256), 0, stream>>>(x, wqa, bqa, wkva, bkva, ws);
  mla_k2<<<dim3(1), dim3(256), 0, stream>>>(kvnw, fcos, fsin, ws);
  mla_k3<<<dim3(H_ * (DN_ + DR_) / 8), dim3(256), 0, stream>>>(qnw, wqb, bqb, fcos, fsin, ws);
  mla_k4<<<dim3(16, H_), dim3(256), 0, stream>>>(wkvb, ws);
  mla_k5<<<dim3(NCH_, B_), dim3(512), 0, stream>>>(kvpre, pepre, ws);
  mla_k6<<<dim3(H_, B_), dim3(256), 0, stream>>>(wkvb, ws);
  mla_k7<<<dim3(DIM_ / 4), dim3(256), 0, stream>>>(wo, wob, ws, out);
}

// Round 2
// 426.555 us; speedup vs baseline: 1.0400x; 1.0400x over previous
//
#include <hip/hip_runtime.h>
#include <math.h>

namespace {
constexpr int B_   = 8;
constexpr int DIM_ = 2048;
constexpr int H_   = 16;
constexpr int QLR_ = 1536;
constexpr int KVLR_= 512;
constexpr int DN_  = 128;
constexpr int DR_  = 64;
constexpr int DV_  = 128;
constexpr int TPRE_= 8191;
constexpr int CE_  = 576;    // KVLR + DR
constexpr int NCH_ = 32;     // chunks over T=8192
constexpr int CT_  = 256;    // t per chunk
constexpr int TS_  = 32;     // rows per LDS subtile
constexpr int RS_  = 580;    // LDS row stride (floats): 576 + 4 pad -> rows hit distinct 16B slots
constexpr int PSTR_= 20;     // p_lds row stride
constexpr float EPS_ = 1e-6f;
constexpr float SCALE_ = 0.07216878364870322f; // (DN+DR)^-0.5

// workspace layout (float offsets)
constexpr size_t WS_QLAT  = 0;
constexpr size_t WS_KVPE  = WS_QLAT  + (size_t)B_*QLR_;
constexpr size_t WS_KVNEW = WS_KVPE  + (size_t)B_*CE_;
constexpr size_t WS_PENEW = WS_KVNEW + (size_t)B_*KVLR_;
constexpr size_t WS_QRS   = WS_PENEW + (size_t)B_*DR_;
constexpr size_t WS_QNOPE = WS_QRS   + (size_t)B_;
constexpr size_t WS_QT    = WS_QNOPE + (size_t)B_*H_*DN_;   // [b][576][16]
constexpr size_t WS_MLOC  = WS_QT    + (size_t)B_*CE_*H_;
constexpr size_t WS_LLOC  = WS_MLOC  + (size_t)B_*H_*NCH_;
constexpr size_t WS_OUT2  = WS_LLOC  + (size_t)B_*H_*NCH_;
constexpr size_t WS_OPART = WS_OUT2  + (size_t)B_*DIM_;     // [b][h][chunk][512]
} // namespace

// ---------------- K1: q_latent = x@wq_a^T + b ; kvpe = x@wkv_a^T + b ----------------
__global__ __launch_bounds__(256) void mla_k1(const float* __restrict__ x,
                                              const float* __restrict__ wqa,
                                              const float* __restrict__ bqa,
                                              const float* __restrict__ wkva,
                                              const float* __restrict__ bkva,
                                              float* __restrict__ ws) {
  const int w = threadIdx.x >> 6, l = threadIdx.x & 63;
  const int r = blockIdx.x * 4 + w;  // 0..2111
  const float* W; const float* bias; float* out; int rr; int ostride;
  if (r < QLR_) { W = wqa;  bias = bqa;  out = ws + WS_QLAT; rr = r;        ostride = QLR_; }
  else          { W = wkva; bias = bkva; out = ws + WS_KVPE; rr = r - QLR_; ostride = CE_;  }
  const float4* wp = (const float4*)(W + (size_t)rr * DIM_);
  const float4* x4 = (const float4*)x;
  float4 wv[8];
#pragma unroll
  for (int j = 0; j < 8; ++j) wv[j] = wp[l + 64 * j];
  float acc[B_];
#pragma unroll
  for (int b = 0; b < B_; ++b) acc[b] = 0.f;
#pragma unroll
  for (int b = 0; b < B_; ++b) {
#pragma unroll
    for (int j = 0; j < 8; ++j) {
      const float4 xv = x4[b * (DIM_ / 4) + l + 64 * j];
      acc[b] = fmaf(wv[j].x, xv.x, fmaf(wv[j].y, xv.y, fmaf(wv[j].z, xv.z, fmaf(wv[j].w, xv.w, acc[b]))));
    }
  }
#pragma unroll
  for (int b = 0; b < B_; ++b)
#pragma unroll
    for (int s = 32; s; s >>= 1) acc[b] += __shfl_xor(acc[b], s);
  if (l == 0) {
    const float b0 = bias[rr];
#pragma unroll
    for (int b = 0; b < B_; ++b) out[b * ostride + rr] = acc[b] + b0;
  }
}

// ---------------- K2: kv rms-norm + k_pe rope + q rms scales ----------------
__global__ __launch_bounds__(256) void mla_k2(const float* __restrict__ kvnw,
                                              const float* __restrict__ fcos,
                                              const float* __restrict__ fsin,
                                              float* __restrict__ ws) {
  const int tid = threadIdx.x;
  const int b = tid >> 5, i = tid & 31;
  const float* kvpe = ws + WS_KVPE + b * CE_;
  float ss = 0.f;
#pragma unroll
  for (int j = 0; j < KVLR_ / 32; ++j) { const float v = kvpe[i + 32 * j]; ss = fmaf(v, v, ss); }
#pragma unroll
  for (int s = 16; s; s >>= 1) ss += __shfl_xor(ss, s, 32);
  const float scale = 1.0f / sqrtf(ss / (float)KVLR_ + EPS_);
  float* kvn = ws + WS_KVNEW + b * KVLR_;
#pragma unroll
  for (int j = 0; j < KVLR_ / 32; ++j) {
    const int c = i + 32 * j;
    kvn[c] = kvpe[c] * kvnw[c] * scale;
  }
  { // rope new k_pe
    const float xr = kvpe[KVLR_ + 2 * i], xi = kvpe[KVLR_ + 2 * i + 1];
    const float c = fcos[i], s = fsin[i];
    float* pen = ws + WS_PENEW + b * DR_;
    pen[2 * i]     = xr * c - xi * s;
    pen[2 * i + 1] = xr * s + xi * c;
  }
  { // q latent rms scale per batch
    const float* p = ws + WS_QLAT + b * QLR_;
    float sq = 0.f;
#pragma unroll
    for (int j = 0; j < QLR_ / 32; ++j) { const float v = p[i + 32 * j]; sq = fmaf(v, v, sq); }
#pragma unroll
    for (int s = 16; s; s >>= 1) sq += __shfl_xor(sq, s, 32);
    if (i == 0) ws[WS_QRS + b] = 1.0f / sqrtf(sq / (float)QLR_ + EPS_);
  }
}

// ---------------- K3: q = rms(q_lat)*g @ wq_b^T + b ; split nope / rope(pe) ----------------
__global__ __launch_bounds__(256) void mla_k3(const float* __restrict__ qnw,
                                              const float* __restrict__ wqb,
                                              const float* __restrict__ bqb,
                                              const float* __restrict__ fcos,
                                              const float* __restrict__ fsin,
                                              float* __restrict__ ws) {
  const int w = threadIdx.x >> 6, l = threadIdx.x & 63;
  const int r0 = blockIdx.x * 8 + w * 2;  // 0..3070
  const float4* w0p = (const float4*)(wqb + (size_t)r0 * QLR_);
  const float4* w1p = (const float4*)(wqb + (size_t)(r0 + 1) * QLR_);
  const float4* g4  = (const float4*)qnw;
  const float4* x4  = (const float4*)(ws + WS_QLAT);
  float4 wg0[6], wg1[6];
#pragma unroll
  for (int j = 0; j < 6; ++j) {
    const int c4 = l + 64 * j;
    const float4 a = w0p[c4], bb = w1p[c4], g = g4[c4];
    wg0[j].x = a.x * g.x; wg0[j].y = a.y * g.y; wg0[j].z = a.z * g.z; wg0[j].w = a.w * g.w;
    wg1[j].x = bb.x * g.x; wg1[j].y = bb.y * g.y; wg1[j].z = bb.z * g.z; wg1[j].w = bb.w * g.w;
  }
  float acc0[B_], acc1[B_];
#pragma unroll
  for (int b = 0; b < B_; ++b) { acc0[b] = 0.f; acc1[b] = 0.f; }
#pragma unroll
  for (int b = 0; b < B_; ++b) {
#pragma unroll
    for (int j = 0; j < 6; ++j) {
      const float4 xv = x4[b * (QLR_ / 4) + l + 64 * j];
      acc0[b] = fmaf(wg0[j].x, xv.x, fmaf(wg0[j].y, xv.y, fmaf(wg0[j].z, xv.z, fmaf(wg0[j].w, xv.w, acc0[b]))));
      acc1[b] = fmaf(wg1[j].x, xv.x, fmaf(wg1[j].y, xv.y, fmaf(wg1[j].z, xv.z, fmaf(wg1[j].w, xv.w, acc1[b]))));
    }
  }
#pragma unroll
  for (int b = 0; b < B_; ++b)
#pragma unroll
    for (int s = 32; s; s >>= 1) {
      acc0[b] += __shfl_xor(acc0[b], s);
      acc1[b] += __shfl_xor(acc1[b], s);
    }
  if (l == 0) {
    const int h = r0 / (DN_ + DR_);
    const int j0 = r0 - h * (DN_ + DR_);
    const float b0 = bqb[r0], b1 = bqb[r0 + 1];
    if (j0 < DN_) {
      float* qn = ws + WS_QNOPE;
#pragma unroll
      for (int b = 0; b < B_; ++b) {
        const float sb = ws[WS_QRS + b];
        qn[(b * H_ + h) * DN_ + j0]     = acc0[b] * sb + b0;
        qn[(b * H_ + h) * DN_ + j0 + 1] = acc1[b] * sb + b1;
      }
    } else {
      const int i = (j0 - DN_) >> 1;
      const float c = fcos[i], s = fsin[i];
      float* qT = ws + WS_QT;
#pragma unroll
      for (int b = 0; b < B_; ++b) {
        const float sb = ws[WS_QRS + b];
        const float xr = acc0[b] * sb + b0, xi = acc1[b] * sb + b1;
        qT[((size_t)b * CE_ + KVLR_ + 2 * i) * H_ + h]     = xr * c - xi * s;
        qT[((size_t)b * CE_ + KVLR_ + 2 * i + 1) * H_ + h] = xr * s + xi * c;
      }
    }
  }
}

// ---------------- K4: q_abs[b][c][h] = sum_d q_nope[b][h][d] * wkv_b[h][d][c] ----------------
__global__ __launch_bounds__(256) void mla_k4(const float* __restrict__ wkvb,
                                              float* __restrict__ ws) {
  __shared__ float red[7 * 32 * B_];
  const int h = blockIdx.y;
  const int strip = blockIdx.x;
  const int tid = threadIdx.x;
  const int c = tid & 31, dg = tid >> 5;
  const int cg = strip * 32 + c;
  const float* qn = ws + WS_QNOPE;
  float acc[B_];
#pragma unroll
  for (int b = 0; b < B_; ++b) acc[b] = 0.f;
  const float* wp = wkvb + (size_t)h * 256 * KVLR_ + cg;
#pragma unroll
  for (int dd = 0; dd < 16; ++dd) {
    const int d = dg * 16 + dd;
    const float wv = wp[(size_t)d * KVLR_];
#pragma unroll
    for (int b = 0; b < B_; ++b) acc[b] = fmaf(qn[(b * H_ + h) * DN_ + d], wv, acc[b]);
  }
  if (dg > 0) {
#pragma unroll
    for (int b = 0; b < B_; ++b) red[(((dg - 1) * 32) + c) * B_ + b] = acc[b];
  }
  __syncthreads();
  if (dg == 0) {
    float* qT = ws + WS_QT;
#pragma unroll
    for (int b = 0; b < B_; ++b) {
      float v = acc[b];
#pragma unroll
      for (int g = 0; g < 7; ++g) v += red[(g * 32 + c) * B_ + b];
      qT[((size_t)b * CE_ + cg) * H_ + h] = v;
    }
  }
}

// ---------------- K5: fused flash-decode, single coalesced kv pass ----------------
// 512 thr, grid (32, 8). Per subtile of 32 rows: coalesced stage -> LDS, scores
// thread<->(t,h) full 576-dot (kv 16-lane broadcast, q from transposed q_lds),
// online softmax (running m,l + o-rescale), PV lane<->c from LDS. kv+pe touch
// HBM exactly once; no phase-C global re-read.
__global__ __launch_bounds__(512, 2) void mla_k5(const float* __restrict__ kvpre,
                                                 const float* __restrict__ pepre,
                                                 float* __restrict__ ws) {
  __shared__ float kv_lds[TS_ * RS_];   // 74.24 KB
  __shared__ float q_lds[H_ * RS_];     // 37.12 KB  (transposed [h][c])
  __shared__ float p_lds[TS_ * PSTR_];  // 2.56 KB
  __shared__ float m_st[H_], l_st[H_], f_st[H_];

  const int b = blockIdx.y;
  const int chunk = blockIdx.x;
  const int t0 = chunk * CT_;
  const int tid = threadIdx.x;

  // --- stage qT (=[c][h]) into q_lds transposed [h][c] ---
  {
    const float4* qsrc = (const float4*)(ws + WS_QT + (size_t)b * CE_ * H_);
#pragma unroll
    for (int it = 0; it < 5; ++it) {
      const int idx = tid + 512 * it;
      if (idx < (CE_ * H_) / 4) {
        const float4 v = qsrc[idx];
        const int c = idx >> 2, h4 = (idx & 3) * 4;
        q_lds[(h4 + 0) * RS_ + c] = v.x;
        q_lds[(h4 + 1) * RS_ + c] = v.y;
        q_lds[(h4 + 2) * RS_ + c] = v.z;
        q_lds[(h4 + 3) * RS_ + c] = v.w;
      }
    }
    if (tid < H_) { m_st[tid] = -3.4e38f; l_st[tid] = 0.f; }
  }

  // flat f4 index decomposition for staging (loop-invariant)
  int fr[9], fw[9];
#pragma unroll
  for (int i = 0; i < 9; ++i) {
    const int f = tid + 512 * i;     // 0..4607 f4 in subtile (32 rows x 144 f4)
    fr[i] = f / 144; fw[i] = f % 144;
  }
  const float* kvnew = ws + WS_KVNEW + b * KVLR_;
  const float* penew = ws + WS_PENEW + b * DR_;

  float4 stg[9];
  auto loadR = [&](int ts) {
#pragma unroll
    for (int i = 0; i < 9; ++i) {
      const int t = t0 + ts * TS_ + fr[i];
      const int wi = fw[i];
      const float* src;
      if (t < TPRE_) {
        src = (wi < 128) ? (kvpre + ((size_t)b * TPRE_ + t) * KVLR_ + wi * 4)
                         : (pepre + ((size_t)b * TPRE_ + t) * DR_ + (wi - 128) * 4);
      } else {
        src = (wi < 128) ? (kvnew + wi * 4) : (penew + (wi - 128) * 4);
      }
      stg[i] = *(const float4*)src;
    }
  };
  loadR(0);

  float o[H_];
#pragma unroll
  for (int h = 0; h < H_; ++h) o[h] = 0.f;

  const int t_sc = tid >> 4, h_sc = tid & 15;  // score mapping: 32 t x 16 h
  const int h2 = tid >> 5, tg = tid & 31;      // softmax mapping: 16 h x 32 t (half-wave)

  for (int ts = 0; ts < CT_ / TS_; ++ts) {     // 8 subtiles
    __syncthreads();                            // previous reads of kv_lds done
    // commit staged regs to LDS
#pragma unroll
    for (int i = 0; i < 9; ++i)
      *(float4*)(kv_lds + fr[i] * RS_ + fw[i] * 4) = stg[i];
    if (ts + 1 < CT_ / TS_) loadR(ts + 1);      // prefetch next subtile (hides HBM under compute)
    __syncthreads();                            // kv_lds ready

    // --- scores: one thread per (t,h), full 576-dim dot from LDS ---
    {
      const float4* kr = (const float4*)(kv_lds + t_sc * RS_);
      const float4* qr = (const float4*)(q_lds + h_sc * RS_);
      float ax = 0.f, ay = 0.f, az = 0.f, aw = 0.f;
#pragma unroll
      for (int c4 = 0; c4 < 144; ++c4) {
        const float4 k = kr[c4], q = qr[c4];
        ax = fmaf(k.x, q.x, ax); ay = fmaf(k.y, q.y, ay);
        az = fmaf(k.z, q.z, az); aw = fmaf(k.w, q.w, aw);
      }
      p_lds[t_sc * PSTR_ + h_sc] = (ax + ay + az + aw) * SCALE_;
    }
    __syncthreads();

    // --- online softmax per head (32 lanes = 32 t, half-wave shuffles) ---
    {
      const float s = p_lds[tg * PSTR_ + h2];
      float msub = s;
#pragma unroll
      for (int d = 16; d; d >>= 1) msub = fmaxf(msub, __shfl_xor(msub, d, 32));
      const float mold = m_st[h2];
      const float mnew = fmaxf(mold, msub);
      const float e = __expf(s - mnew);
      float lsum = e;
#pragma unroll
      for (int d = 16; d; d >>= 1) lsum += __shfl_xor(lsum, d, 32);
      p_lds[tg * PSTR_ + h2] = e;
      if (tg == 0) {
        const float fac = __expf(mold - mnew);
        f_st[h2] = fac;
        l_st[h2] = l_st[h2] * fac + lsum;
        m_st[h2] = mnew;
      }
    }
    __syncthreads();

    // --- PV accumulate: lane owns c = tid (512 c), o[16] heads ---
    {
      const int c = tid;
      const float4 f0 = *(const float4*)&f_st[0];
      const float4 f1 = *(const float4*)&f_st[4];
      const float4 f2 = *(const float4*)&f_st[8];
      const float4 f3 = *(const float4*)&f_st[12];
      o[0] *= f0.x; o[1] *= f0.y; o[2] *= f0.z; o[3] *= f0.w;
      o[4] *= f1.x; o[5] *= f1.y; o[6] *= f1.z; o[7] *= f1.w;
      o[8] *= f2.x; o[9] *= f2.y; o[10] *= f2.z; o[11] *= f2.w;
      o[12] *= f3.x; o[13] *= f3.y; o[14] *= f3.z; o[15] *= f3.w;
#pragma unroll 8
      for (int t = 0; t < TS_; ++t) {
        const float kvv = kv_lds[t * RS_ + c];
        const float4 p0 = *(const float4*)(p_lds + t * PSTR_);
        const float4 p1 = *(const float4*)(p_lds + t * PSTR_ + 4);
        const float4 p2 = *(const float4*)(p_lds + t * PSTR_ + 8);
        const float4 p3 = *(const float4*)(p_lds + t * PSTR_ + 12);
        o[0]  = fmaf(p0.x, kvv, o[0]);  o[1]  = fmaf(p0.y, kvv, o[1]);
        o[2]  = fmaf(p0.z, kvv, o[2]);  o[3]  = fmaf(p0.w, kvv, o[3]);
        o[4]  = fmaf(p1.x, kvv, o[4]);  o[5]  = fmaf(p1.y, kvv, o[5]);
        o[6]  = fmaf(p1.z, kvv, o[6]);  o[7]  = fmaf(p1.w, kvv, o[7]);
        o[8]  = fmaf(p2.x, kvv, o[8]);  o[9]  = fmaf(p2.y, kvv, o[9]);
        o[10] = fmaf(p2.z, kvv, o[10]); o[11] = fmaf(p2.w, kvv, o[11]);
        o[12] = fmaf(p3.x, kvv, o[12]); o[13] = fmaf(p3.y, kvv, o[13]);
        o[14] = fmaf(p3.z, kvv, o[14]); o[15] = fmaf(p3.w, kvv, o[15]);
      }
    }
  }

  // --- write chunk partials ---
  {
    const int c = tid;
    float* Op = ws + WS_OPART + ((size_t)(b * H_) * NCH_ + chunk) * KVLR_;
#pragma unroll
    for (int h = 0; h < H_; ++h)
      Op[(size_t)h * NCH_ * KVLR_ + c] = o[h];
    if (tid < H_) {
      ws[WS_MLOC + (b * H_ + tid) * NCH_ + chunk] = m_st[tid];
      ws[WS_LLOC + (b * H_ + tid) * NCH_ + chunk] = l_st[tid];
    }
  }
}

// ---------------- K6: combine partials + project through wkv_b[:,128:,:] ----------------
__global__ __launch_bounds__(256) void mla_k6(const float* __restrict__ wkvb,
                                              float* __restrict__ ws) {
  const int h = blockIdx.x, b = blockIdx.y;
  __shared__ float wgt[NCH_];
  __shared__ float ao[KVLR_];
  __shared__ float Linv;
  const int tid = threadIdx.x;
  if (tid < NCH_) {   // 32 lanes: combine weights
    const float m = ws[WS_MLOC + (b * H_ + h) * NCH_ + tid];
    float M = m;
#pragma unroll
    for (int s = 16; s; s >>= 1) M = fmaxf(M, __shfl_xor(M, s, 32));
    const float wv = __expf(m - M);
    wgt[tid] = wv;
    float lv = ws[WS_LLOC + (b * H_ + h) * NCH_ + tid] * wv;
#pragma unroll
    for (int s = 16; s; s >>= 1) lv += __shfl_xor(lv, s, 32);
    if (tid == 0) Linv = 1.0f / lv;
  }
  __syncthreads();
  const float* Ob = ws + WS_OPART + (size_t)(b * H_ + h) * NCH_ * KVLR_;
  float s0 = 0.f, s1 = 0.f;
#pragma unroll 4
  for (int i = 0; i < NCH_; ++i) {
    const float wv = wgt[i];
    s0 = fmaf(wv, Ob[(size_t)i * KVLR_ + tid], s0);
    s1 = fmaf(wv, Ob[(size_t)i * KVLR_ + tid + 256], s1);
  }
  const float li = Linv;
  ao[tid] = s0 * li;
  ao[tid + 256] = s1 * li;
  __syncthreads();
  const int v = tid >> 1, half = tid & 1;
  const float* w2 = wkvb + ((size_t)h * 256 + DN_ + v) * KVLR_ + half * 256;
  const float* a = ao + half * 256;
  float s = 0.f;
#pragma unroll
  for (int c = 0; c < 256; c += 4) {
    const float4 wv = *(const float4*)(w2 + c);
    s = fmaf(wv.x, a[c], s);
    s = fmaf(wv.y, a[c + 1], s);
    s = fmaf(wv.z, a[c + 2], s);
    s = fmaf(wv.w, a[c + 3], s);
  }
  s += __shfl_xor(s, 1);
  if (half == 0) ws[WS_OUT2 + b * DIM_ + h * DV_ + v] = s;
}

// ---------------- K7: y = out2 @ wo^T + wo_b ----------------
__global__ __launch_bounds__(256) void mla_k7(const float* __restrict__ wo,
                                              const float* __restrict__ wob,
                                              const float* __restrict__ ws,
                                              float* __restrict__ out) {
  const int w = threadIdx.x >> 6, l = threadIdx.x & 63;
  const int r = blockIdx.x * 4 + w;  // 0..2047
  const float4* wp = (const float4*)(wo + (size_t)r * DIM_);
  const float4* x4 = (const float4*)(ws + WS_OUT2);
  float4 wv[8];
#pragma unroll
  for (int j = 0; j < 8; ++j) wv[j] = wp[l + 64 * j];
  float acc[B_];
#pragma unroll
  for (int b = 0; b < B_; ++b) acc[b] = 0.f;
#pragma unroll
  for (int b = 0; b < B_; ++b) {
#pragma unroll
    for (int j = 0; j < 8; ++j) {
      const float4 xv = x4[b * (DIM_ / 4) + l + 64 * j];
      acc[b] = fmaf(wv[j].x, xv.x, fmaf(wv[j].y, xv.y, fmaf(wv[j].z, xv.z, fmaf(wv[j].w, xv.w, acc[b]))));
    }
  }
#pragma unroll
  for (int b = 0; b < B_; ++b)
#pragma unroll
    for (int s = 32; s; s >>= 1) acc[b] += __shfl_xor(acc[b], s);
  if (l == 0) {
    const float b0 = wob[r];
#pragma unroll
    for (int b = 0; b < B_; ++b) out[b * DIM_ + r] = acc[b] + b0;
  }
}

extern "C" void kernel_launch(void* const* d_in, const int* in_sizes, int n_in,
                              void* d_out, int out_size, void* d_ws, size_t ws_size,
                              hipStream_t stream) {
  (void)in_sizes; (void)n_in; (void)out_size; (void)ws_size;
  const float* x     = (const float*)d_in[0];
  const float* fcos  = (const float*)d_in[2];
  const float* fsin  = (const float*)d_in[3];
  const float* kvpre = (const float*)d_in[4];
  const float* pepre = (const float*)d_in[5];
  const float* wqa   = (const float*)d_in[6];
  const float* bqa   = (const float*)d_in[7];
  const float* qnw   = (const float*)d_in[8];
  const float* wqb   = (const float*)d_in[9];
  const float* bqb   = (const float*)d_in[10];
  const float* wkva  = (const float*)d_in[11];
  const float* bkva  = (const float*)d_in[12];
  const float* kvnw  = (const float*)d_in[13];
  const float* wkvb  = (const float*)d_in[14];
  const float* wo    = (const float*)d_in[15];
  const float* wob   = (const float*)d_in[16];
  float* ws  = (float*)d_ws;
  float* out = (float*)d_out;

  mla_k1<<<dim3((QLR_ + CE_) / 4), dim3(256), 0, stream>>>(x, wqa, bqa, wkva, bkva, ws);
  mla_k2<<<dim3(1), dim3(256), 0, stream>>>(kvnw, fcos, fsin, ws);
  mla_k3<<<dim3(H_ * (DN_ + DR_) / 8), dim3(256), 0, stream>>>(qnw, wqb, bqb, fcos, fsin, ws);
  mla_k4<<<dim3(16, H_), dim3(256), 0, stream>>>(wkvb, ws);
  mla_k5<<<dim3(NCH_, B_), dim3(512), 0, stream>>>(kvpre, pepre, ws);
  mla_k6<<<dim3(H_, B_), dim3(256), 0, stream>>>(wkvb, ws);
  mla_k7<<<dim3(DIM_ / 4), dim3(256), 0, stream>>>(wo, wob, ws, out);
}

// Round 3
// 366.595 us; speedup vs baseline: 1.2101x; 1.1636x over previous
//
#include <hip/hip_runtime.h>
#include <math.h>

namespace {
constexpr int B_   = 8;
constexpr int DIM_ = 2048;
constexpr int H_   = 16;
constexpr int QLR_ = 1536;
constexpr int KVLR_= 512;
constexpr int DN_  = 128;
constexpr int DR_  = 64;
constexpr int DV_  = 128;
constexpr int TPRE_= 8191;
constexpr int CE_  = 576;    // KVLR + DR
constexpr int NCH_ = 32;     // chunks over T=8192
constexpr int CT_  = 256;    // t per chunk
constexpr int TS_  = 16;     // rows per LDS subtile (double-buffered)
constexpr int PSTR_= 20;     // p_lds row stride
constexpr float EPS_ = 1e-6f;
constexpr float SCALE_ = 0.07216878364870322f; // (DN+DR)^-0.5

// workspace layout (float offsets)
constexpr size_t WS_QLAT  = 0;
constexpr size_t WS_KVPE  = WS_QLAT  + (size_t)B_*QLR_;
constexpr size_t WS_KVNEW = WS_KVPE  + (size_t)B_*CE_;
constexpr size_t WS_PENEW = WS_KVNEW + (size_t)B_*KVLR_;
constexpr size_t WS_QRS   = WS_PENEW + (size_t)B_*DR_;
constexpr size_t WS_QNOPE = WS_QRS   + (size_t)B_;
constexpr size_t WS_QT    = WS_QNOPE + (size_t)B_*H_*DN_;   // [b][576][16]
constexpr size_t WS_MLOC  = WS_QT    + (size_t)B_*CE_*H_;
constexpr size_t WS_LLOC  = WS_MLOC  + (size_t)B_*H_*NCH_;
constexpr size_t WS_OUT2  = WS_LLOC  + (size_t)B_*H_*NCH_;
constexpr size_t WS_OPART = WS_OUT2  + (size_t)B_*DIM_;     // [b][h][chunk][512]
} // namespace

__device__ __forceinline__ void gload16(const float* src, float* ldsDst) {
  __builtin_amdgcn_global_load_lds((const __attribute__((address_space(1))) void*)src,
                                   (__attribute__((address_space(3))) void*)ldsDst,
                                   16, 0, 0);
}

// ---------------- K1: q_latent = x@wq_a^T + b ; kvpe = x@wkv_a^T + b ----------------
__global__ __launch_bounds__(256) void mla_k1(const float* __restrict__ x,
                                              const float* __restrict__ wqa,
                                              const float* __restrict__ bqa,
                                              const float* __restrict__ wkva,
                                              const float* __restrict__ bkva,
                                              float* __restrict__ ws) {
  const int w = threadIdx.x >> 6, l = threadIdx.x & 63;
  const int r = blockIdx.x * 4 + w;  // 0..2111
  const float* W; const float* bias; float* out; int rr; int ostride;
  if (r < QLR_) { W = wqa;  bias = bqa;  out = ws + WS_QLAT; rr = r;        ostride = QLR_; }
  else          { W = wkva; bias = bkva; out = ws + WS_KVPE; rr = r - QLR_; ostride = CE_;  }
  const float4* wp = (const float4*)(W + (size_t)rr * DIM_);
  const float4* x4 = (const float4*)x;
  float4 wv[8];
#pragma unroll
  for (int j = 0; j < 8; ++j) wv[j] = wp[l + 64 * j];
  float acc[B_];
#pragma unroll
  for (int b = 0; b < B_; ++b) acc[b] = 0.f;
#pragma unroll
  for (int b = 0; b < B_; ++b) {
#pragma unroll
    for (int j = 0; j < 8; ++j) {
      const float4 xv = x4[b * (DIM_ / 4) + l + 64 * j];
      acc[b] = fmaf(wv[j].x, xv.x, fmaf(wv[j].y, xv.y, fmaf(wv[j].z, xv.z, fmaf(wv[j].w, xv.w, acc[b]))));
    }
  }
#pragma unroll
  for (int b = 0; b < B_; ++b)
#pragma unroll
    for (int s = 32; s; s >>= 1) acc[b] += __shfl_xor(acc[b], s);
  if (l == 0) {
    const float b0 = bias[rr];
#pragma unroll
    for (int b = 0; b < B_; ++b) out[b * ostride + rr] = acc[b] + b0;
  }
}

// ---------------- K2: kv rms-norm + k_pe rope + q rms scales ----------------
__global__ __launch_bounds__(256) void mla_k2(const float* __restrict__ kvnw,
                                              const float* __restrict__ fcos,
                                              const float* __restrict__ fsin,
                                              float* __restrict__ ws) {
  const int tid = threadIdx.x;
  const int b = tid >> 5, i = tid & 31;
  const float* kvpe = ws + WS_KVPE + b * CE_;
  float ss = 0.f;
#pragma unroll
  for (int j = 0; j < KVLR_ / 32; ++j) { const float v = kvpe[i + 32 * j]; ss = fmaf(v, v, ss); }
#pragma unroll
  for (int s = 16; s; s >>= 1) ss += __shfl_xor(ss, s, 32);
  const float scale = 1.0f / sqrtf(ss / (float)KVLR_ + EPS_);
  float* kvn = ws + WS_KVNEW + b * KVLR_;
#pragma unroll
  for (int j = 0; j < KVLR_ / 32; ++j) {
    const int c = i + 32 * j;
    kvn[c] = kvpe[c] * kvnw[c] * scale;
  }
  { // rope new k_pe
    const float xr = kvpe[KVLR_ + 2 * i], xi = kvpe[KVLR_ + 2 * i + 1];
    const float c = fcos[i], s = fsin[i];
    float* pen = ws + WS_PENEW + b * DR_;
    pen[2 * i]     = xr * c - xi * s;
    pen[2 * i + 1] = xr * s + xi * c;
  }
  { // q latent rms scale per batch
    const float* p = ws + WS_QLAT + b * QLR_;
    float sq = 0.f;
#pragma unroll
    for (int j = 0; j < QLR_ / 32; ++j) { const float v = p[i + 32 * j]; sq = fmaf(v, v, sq); }
#pragma unroll
    for (int s = 16; s; s >>= 1) sq += __shfl_xor(sq, s, 32);
    if (i == 0) ws[WS_QRS + b] = 1.0f / sqrtf(sq / (float)QLR_ + EPS_);
  }
}

// ---------------- K3: q = rms(q_lat)*g @ wq_b^T + b ; split nope / rope(pe) ----------------
__global__ __launch_bounds__(256) void mla_k3(const float* __restrict__ qnw,
                                              const float* __restrict__ wqb,
                                              const float* __restrict__ bqb,
                                              const float* __restrict__ fcos,
                                              const float* __restrict__ fsin,
                                              float* __restrict__ ws) {
  const int w = threadIdx.x >> 6, l = threadIdx.x & 63;
  const int r0 = blockIdx.x * 8 + w * 2;  // 0..3070
  const float4* w0p = (const float4*)(wqb + (size_t)r0 * QLR_);
  const float4* w1p = (const float4*)(wqb + (size_t)(r0 + 1) * QLR_);
  const float4* g4  = (const float4*)qnw;
  const float4* x4  = (const float4*)(ws + WS_QLAT);
  float4 wg0[6], wg1[6];
#pragma unroll
  for (int j = 0; j < 6; ++j) {
    const int c4 = l + 64 * j;
    const float4 a = w0p[c4], bb = w1p[c4], g = g4[c4];
    wg0[j].x = a.x * g.x; wg0[j].y = a.y * g.y; wg0[j].z = a.z * g.z; wg0[j].w = a.w * g.w;
    wg1[j].x = bb.x * g.x; wg1[j].y = bb.y * g.y; wg1[j].z = bb.z * g.z; wg1[j].w = bb.w * g.w;
  }
  float acc0[B_], acc1[B_];
#pragma unroll
  for (int b = 0; b < B_; ++b) { acc0[b] = 0.f; acc1[b] = 0.f; }
#pragma unroll
  for (int b = 0; b < B_; ++b) {
#pragma unroll
    for (int j = 0; j < 6; ++j) {
      const float4 xv = x4[b * (QLR_ / 4) + l + 64 * j];
      acc0[b] = fmaf(wg0[j].x, xv.x, fmaf(wg0[j].y, xv.y, fmaf(wg0[j].z, xv.z, fmaf(wg0[j].w, xv.w, acc0[b]))));
      acc1[b] = fmaf(wg1[j].x, xv.x, fmaf(wg1[j].y, xv.y, fmaf(wg1[j].z, xv.z, fmaf(wg1[j].w, xv.w, acc1[b]))));
    }
  }
#pragma unroll
  for (int b = 0; b < B_; ++b)
#pragma unroll
    for (int s = 32; s; s >>= 1) {
      acc0[b] += __shfl_xor(acc0[b], s);
      acc1[b] += __shfl_xor(acc1[b], s);
    }
  if (l == 0) {
    const int h = r0 / (DN_ + DR_);
    const int j0 = r0 - h * (DN_ + DR_);
    const float b0 = bqb[r0], b1 = bqb[r0 + 1];
    if (j0 < DN_) {
      float* qn = ws + WS_QNOPE;
#pragma unroll
      for (int b = 0; b < B_; ++b) {
        const float sb = ws[WS_QRS + b];
        qn[(b * H_ + h) * DN_ + j0]     = acc0[b] * sb + b0;
        qn[(b * H_ + h) * DN_ + j0 + 1] = acc1[b] * sb + b1;
      }
    } else {
      const int i = (j0 - DN_) >> 1;
      const float c = fcos[i], s = fsin[i];
      float* qT = ws + WS_QT;
#pragma unroll
      for (int b = 0; b < B_; ++b) {
        const float sb = ws[WS_QRS + b];
        const float xr = acc0[b] * sb + b0, xi = acc1[b] * sb + b1;
        qT[((size_t)b * CE_ + KVLR_ + 2 * i) * H_ + h]     = xr * c - xi * s;
        qT[((size_t)b * CE_ + KVLR_ + 2 * i + 1) * H_ + h] = xr * s + xi * c;
      }
    }
  }
}

// ---------------- K4: q_abs[b][c][h] = sum_d q_nope[b][h][d] * wkv_b[h][d][c] ----------------
__global__ __launch_bounds__(256) void mla_k4(const float* __restrict__ wkvb,
                                              float* __restrict__ ws) {
  __shared__ float red[7 * 32 * B_];
  const int h = blockIdx.y;
  const int strip = blockIdx.x;
  const int tid = threadIdx.x;
  const int c = tid & 31, dg = tid >> 5;
  const int cg = strip * 32 + c;
  const float* qn = ws + WS_QNOPE;
  float acc[B_];
#pragma unroll
  for (int b = 0; b < B_; ++b) acc[b] = 0.f;
  const float* wp = wkvb + (size_t)h * 256 * KVLR_ + cg;
#pragma unroll
  for (int dd = 0; dd < 16; ++dd) {
    const int d = dg * 16 + dd;
    const float wv = wp[(size_t)d * KVLR_];
#pragma unroll
    for (int b = 0; b < B_; ++b) acc[b] = fmaf(qn[(b * H_ + h) * DN_ + d], wv, acc[b]);
  }
  if (dg > 0) {
#pragma unroll
    for (int b = 0; b < B_; ++b) red[(((dg - 1) * 32) + c) * B_ + b] = acc[b];
  }
  __syncthreads();
  if (dg == 0) {
    float* qT = ws + WS_QT;
#pragma unroll
    for (int b = 0; b < B_; ++b) {
      float v = acc[b];
#pragma unroll
      for (int g = 0; g < 7; ++g) v += red[(g * 32 + c) * B_ + b];
      qT[((size_t)b * CE_ + cg) * H_ + h] = v;
    }
  }
}

// ---------------- K5: fused flash-decode, register-tiled, global_load_lds staging ----------------
// 512 thr, grid (32, 8). TS=16 double-buffered subtiles staged via global_load_lds
// (no staging VGPRs -> no spill; prefetch overlaps compute). Score: thread =
// (t-pair, h-quad, c-eighth), 6 b128 per 32 FMA; 3-stage shfl reduce over c-split.
// PV: thread = (c-quad, h-quad), o[4][4] persists over t: 2 b128 per 16 FMA.
__global__ __launch_bounds__(512, 2) void mla_k5(const float* __restrict__ kvpre,
                                                 const float* __restrict__ pepre,
                                                 float* __restrict__ ws) {
  __shared__ float kv_lds[2][TS_ * CE_];  // 2 x 16 x 576 = 72 KB, linear (gload dst)
  __shared__ float q_lds[9248];           // [c][16h] + 4*(c/72) skew, 36.2 KB
  __shared__ float p_lds[TS_ * PSTR_];    // 1.25 KB
  __shared__ float m_st[H_], l_st[H_], f_st[H_];

  const int b = blockIdx.y;
  const int chunk = blockIdx.x;
  const int t0 = chunk * CT_;
  const int tid = threadIdx.x;
  const int w = tid >> 6, l = tid & 63;
  const float* kvnew = ws + WS_KVNEW + b * KVLR_;
  const float* penew = ws + WS_PENEW + b * DR_;

  auto stageKV = [&](float* buf, int s) {
    const int ts0 = t0 + s * TS_;
    for (int i = w; i < (TS_ * CE_) / 256; i += 8) {  // 36 gload16 instrs, wave-strided
      const int f = i * 64 + l;                        // f4 index in subtile
      const int tl = f / 144;
      const int c4 = f - tl * 144;
      const int tg = ts0 + tl;
      const float* src;
      if (tg < TPRE_) {
        src = (c4 < 128) ? (kvpre + ((size_t)b * TPRE_ + tg) * KVLR_ + 4 * c4)
                         : (pepre + ((size_t)b * TPRE_ + tg) * DR_ + 4 * (c4 - 128));
      } else {
        src = (c4 < 128) ? (kvnew + 4 * c4) : (penew + 4 * (c4 - 128));
      }
      gload16(src, buf + (size_t)i * 256);
    }
  };

  stageKV(kv_lds[0], 0);   // start HBM early

  // --- stage qT [c][h] -> q_lds [c*16 + hq*4 + 4*(c/72)] ---
  {
    const float4* qsrc = (const float4*)(ws + WS_QT + (size_t)b * CE_ * H_);
#pragma unroll
    for (int k = 0; k < 5; ++k) {
      const int idx = tid + 512 * k;
      if (idx < (CE_ * H_) / 4) {
        const float4 v = qsrc[idx];
        const int c = idx >> 2, hq = idx & 3;
        *(float4*)(q_lds + c * 16 + hq * 4 + 4 * (c / 72)) = v;
      }
    }
    if (tid < H_) { m_st[tid] = -3.4e38f; l_st[tid] = 0.f; }
  }

  // score roles (threads 0..255 = waves 0..3)
  const int c8 = l >> 3;
  const int rlo = l & 7;
  const int t2 = ((w & 3) << 1) + (rlo >> 2);  // 0..7 -> rows 2*t2, 2*t2+1
  const int h4 = rlo & 3;
  // PV roles (all threads)
  const int c4p = tid >> 2, h4p = tid & 3;

  float o[4][4];
#pragma unroll
  for (int cc = 0; cc < 4; ++cc)
#pragma unroll
    for (int hh = 0; hh < 4; ++hh) o[cc][hh] = 0.f;

  for (int s = 0; s < CT_ / TS_; ++s) {  // 16 subtiles
    __syncthreads();                      // drains stage(s) (vmcnt) + prior LDS ops
    if (s + 1 < CT_ / TS_) stageKV(kv_lds[(s + 1) & 1], s + 1);  // prefetch
    const float* bufc = kv_lds[s & 1];

    // --- scores (waves 0-3): full 576-dot split 8-ways over c ---
    if (tid < 256) {
      const float* r0 = bufc + (2 * t2) * CE_ + c8 * 72;
      const float* r1 = r0 + CE_;
      const float* qb = q_lds + (c8 * 72) * 16 + 4 * c8 + 4 * h4;
      float acc0[4] = {0.f, 0.f, 0.f, 0.f};
      float acc1[4] = {0.f, 0.f, 0.f, 0.f};
#pragma unroll
      for (int j = 0; j < 18; ++j) {
        const float4 k0 = *(const float4*)(r0 + 4 * j);
        const float4 k1 = *(const float4*)(r1 + 4 * j);
        const float4 q0 = *(const float4*)(qb + (4 * j + 0) * 16);
        const float4 q1 = *(const float4*)(qb + (4 * j + 1) * 16);
        const float4 q2 = *(const float4*)(qb + (4 * j + 2) * 16);
        const float4 q3 = *(const float4*)(qb + (4 * j + 3) * 16);
        acc0[0] = fmaf(k0.x, q0.x, fmaf(k0.y, q1.x, fmaf(k0.z, q2.x, fmaf(k0.w, q3.x, acc0[0]))));
        acc0[1] = fmaf(k0.x, q0.y, fmaf(k0.y, q1.y, fmaf(k0.z, q2.y, fmaf(k0.w, q3.y, acc0[1]))));
        acc0[2] = fmaf(k0.x, q0.z, fmaf(k0.y, q1.z, fmaf(k0.z, q2.z, fmaf(k0.w, q3.z, acc0[2]))));
        acc0[3] = fmaf(k0.x, q0.w, fmaf(k0.y, q1.w, fmaf(k0.z, q2.w, fmaf(k0.w, q3.w, acc0[3]))));
        acc1[0] = fmaf(k1.x, q0.x, fmaf(k1.y, q1.x, fmaf(k1.z, q2.x, fmaf(k1.w, q3.x, acc1[0]))));
        acc1[1] = fmaf(k1.x, q0.y, fmaf(k1.y, q1.y, fmaf(k1.z, q2.y, fmaf(k1.w, q3.y, acc1[1]))));
        acc1[2] = fmaf(k1.x, q0.z, fmaf(k1.y, q1.z, fmaf(k1.z, q2.z, fmaf(k1.w, q3.z, acc1[2]))));
        acc1[3] = fmaf(k1.x, q0.w, fmaf(k1.y, q1.w, fmaf(k1.z, q2.w, fmaf(k1.w, q3.w, acc1[3]))));
      }
#pragma unroll
      for (int d = 8; d <= 32; d <<= 1) {
#pragma unroll
        for (int hh = 0; hh < 4; ++hh) {
          acc0[hh] += __shfl_xor(acc0[hh], d);
          acc1[hh] += __shfl_xor(acc1[hh], d);
        }
      }
      if (c8 == 0) {
        float4 v0, v1;
        v0.x = acc0[0] * SCALE_; v0.y = acc0[1] * SCALE_;
        v0.z = acc0[2] * SCALE_; v0.w = acc0[3] * SCALE_;
        v1.x = acc1[0] * SCALE_; v1.y = acc1[1] * SCALE_;
        v1.z = acc1[2] * SCALE_; v1.w = acc1[3] * SCALE_;
        *(float4*)(p_lds + (2 * t2) * PSTR_ + 4 * h4)     = v0;
        *(float4*)(p_lds + (2 * t2 + 1) * PSTR_ + 4 * h4) = v1;
      }
    }
    __syncthreads();

    // --- online softmax (threads 0..255: 16 h x 16 t) ---
    if (tid < 256) {
      const int h2 = tid >> 4, tg = tid & 15;
      const float sv = p_lds[tg * PSTR_ + h2];
      float msub = sv;
#pragma unroll
      for (int d = 1; d < 16; d <<= 1) msub = fmaxf(msub, __shfl_xor(msub, d, 16));
      const float mold = m_st[h2];
      const float mnew = fmaxf(mold, msub);
      const float e = __expf(sv - mnew);
      float lsum = e;
#pragma unroll
      for (int d = 1; d < 16; d <<= 1) lsum += __shfl_xor(lsum, d, 16);
      p_lds[tg * PSTR_ + h2] = e;
      if (tg == 0) {
        const float fac = __expf(mold - mnew);
        f_st[h2] = fac;
        l_st[h2] = l_st[h2] * fac + lsum;
        m_st[h2] = mnew;
      }
    }
    __syncthreads();

    // --- PV accumulate (all 512 threads): o[c-quad][h-quad] ---
    {
      const float4 fv = *(const float4*)(f_st + 4 * h4p);
#pragma unroll
      for (int cc = 0; cc < 4; ++cc) {
        o[cc][0] *= fv.x; o[cc][1] *= fv.y; o[cc][2] *= fv.z; o[cc][3] *= fv.w;
      }
#pragma unroll
      for (int t = 0; t < TS_; ++t) {
        const float4 kq = *(const float4*)(bufc + t * CE_ + 4 * c4p);
        const float4 pq = *(const float4*)(p_lds + t * PSTR_ + 4 * h4p);
        o[0][0] = fmaf(pq.x, kq.x, o[0][0]); o[0][1] = fmaf(pq.y, kq.x, o[0][1]);
        o[0][2] = fmaf(pq.z, kq.x, o[0][2]); o[0][3] = fmaf(pq.w, kq.x, o[0][3]);
        o[1][0] = fmaf(pq.x, kq.y, o[1][0]); o[1][1] = fmaf(pq.y, kq.y, o[1][1]);
        o[1][2] = fmaf(pq.z, kq.y, o[1][2]); o[1][3] = fmaf(pq.w, kq.y, o[1][3]);
        o[2][0] = fmaf(pq.x, kq.z, o[2][0]); o[2][1] = fmaf(pq.y, kq.z, o[2][1]);
        o[2][2] = fmaf(pq.z, kq.z, o[2][2]); o[2][3] = fmaf(pq.w, kq.z, o[2][3]);
        o[3][0] = fmaf(pq.x, kq.w, o[3][0]); o[3][1] = fmaf(pq.y, kq.w, o[3][1]);
        o[3][2] = fmaf(pq.z, kq.w, o[3][2]); o[3][3] = fmaf(pq.w, kq.w, o[3][3]);
      }
    }
  }

  // --- write chunk partials ---
  {
    float* Op = ws + WS_OPART;
#pragma unroll
    for (int hh = 0; hh < 4; ++hh) {
      const int h = 4 * h4p + hh;
      float4 v;
      v.x = o[0][hh]; v.y = o[1][hh]; v.z = o[2][hh]; v.w = o[3][hh];
      *(float4*)(Op + ((size_t)(b * H_ + h) * NCH_ + chunk) * KVLR_ + 4 * c4p) = v;
    }
    if (tid < H_) {
      ws[WS_MLOC + (b * H_ + tid) * NCH_ + chunk] = m_st[tid];
      ws[WS_LLOC + (b * H_ + tid) * NCH_ + chunk] = l_st[tid];
    }
  }
}

// ---------------- K6: combine partials + project through wkv_b[:,128:,:] ----------------
__global__ __launch_bounds__(256) void mla_k6(const float* __restrict__ wkvb,
                                              float* __restrict__ ws) {
  const int h = blockIdx.x, b = blockIdx.y;
  __shared__ float wgt[NCH_];
  __shared__ float ao[KVLR_];
  __shared__ float Linv;
  const int tid = threadIdx.x;
  if (tid < NCH_) {   // 32 lanes: combine weights
    const float m = ws[WS_MLOC + (b * H_ + h) * NCH_ + tid];
    float M = m;
#pragma unroll
    for (int s = 16; s; s >>= 1) M = fmaxf(M, __shfl_xor(M, s, 32));
    const float wv = __expf(m - M);
    wgt[tid] = wv;
    float lv = ws[WS_LLOC + (b * H_ + h) * NCH_ + tid] * wv;
#pragma unroll
    for (int s = 16; s; s >>= 1) lv += __shfl_xor(lv, s, 32);
    if (tid == 0) Linv = 1.0f / lv;
  }
  __syncthreads();
  const float* Ob = ws + WS_OPART + (size_t)(b * H_ + h) * NCH_ * KVLR_;
  float s0 = 0.f, s1 = 0.f;
#pragma unroll 4
  for (int i = 0; i < NCH_; ++i) {
    const float wv = wgt[i];
    s0 = fmaf(wv, Ob[(size_t)i * KVLR_ + tid], s0);
    s1 = fmaf(wv, Ob[(size_t)i * KVLR_ + tid + 256], s1);
  }
  const float li = Linv;
  ao[tid] = s0 * li;
  ao[tid + 256] = s1 * li;
  __syncthreads();
  const int v = tid >> 1, half = tid & 1;
  const float* w2 = wkvb + ((size_t)h * 256 + DN_ + v) * KVLR_ + half * 256;
  const float* a = ao + half * 256;
  float s = 0.f;
#pragma unroll
  for (int c = 0; c < 256; c += 4) {
    const float4 wv = *(const float4*)(w2 + c);
    s = fmaf(wv.x, a[c], s);
    s = fmaf(wv.y, a[c + 1], s);
    s = fmaf(wv.z, a[c + 2], s);
    s = fmaf(wv.w, a[c + 3], s);
  }
  s += __shfl_xor(s, 1);
  if (half == 0) ws[WS_OUT2 + b * DIM_ + h * DV_ + v] = s;
}

// ---------------- K7: y = out2 @ wo^T + wo_b ----------------
__global__ __launch_bounds__(256) void mla_k7(const float* __restrict__ wo,
                                              const float* __restrict__ wob,
                                              const float* __restrict__ ws,
                                              float* __restrict__ out) {
  const int w = threadIdx.x >> 6, l = threadIdx.x & 63;
  const int r = blockIdx.x * 4 + w;  // 0..2047
  const float4* wp = (const float4*)(wo + (size_t)r * DIM_);
  const float4* x4 = (const float4*)(ws + WS_OUT2);
  float4 wv[8];
#pragma unroll
  for (int j = 0; j < 8; ++j) wv[j] = wp[l + 64 * j];
  float acc[B_];
#pragma unroll
  for (int b = 0; b < B_; ++b) acc[b] = 0.f;
#pragma unroll
  for (int b = 0; b < B_; ++b) {
#pragma unroll
    for (int j = 0; j < 8; ++j) {
      const float4 xv = x4[b * (DIM_ / 4) + l + 64 * j];
      acc[b] = fmaf(wv[j].x, xv.x, fmaf(wv[j].y, xv.y, fmaf(wv[j].z, xv.z, fmaf(wv[j].w, xv.w, acc[b]))));
    }
  }
#pragma unroll
  for (int b = 0; b < B_; ++b)
#pragma unroll
    for (int s = 32; s; s >>= 1) acc[b] += __shfl_xor(acc[b], s);
  if (l == 0) {
    const float b0 = wob[r];
#pragma unroll
    for (int b = 0; b < B_; ++b) out[b * DIM_ + r] = acc[b] + b0;
  }
}

extern "C" void kernel_launch(void* const* d_in, const int* in_sizes, int n_in,
                              void* d_out, int out_size, void* d_ws, size_t ws_size,
                              hipStream_t stream) {
  (void)in_sizes; (void)n_in; (void)out_size; (void)ws_size;
  const float* x     = (const float*)d_in[0];
  const float* fcos  = (const float*)d_in[2];
  const float* fsin  = (const float*)d_in[3];
  const float* kvpre = (const float*)d_in[4];
  const float* pepre = (const float*)d_in[5];
  const float* wqa   = (const float*)d_in[6];
  const float* bqa   = (const float*)d_in[7];
  const float* qnw   = (const float*)d_in[8];
  const float* wqb   = (const float*)d_in[9];
  const float* bqb   = (const float*)d_in[10];
  const float* wkva  = (const float*)d_in[11];
  const float* bkva  = (const float*)d_in[12];
  const float* kvnw  = (const float*)d_in[13];
  const float* wkvb  = (const float*)d_in[14];
  const float* wo    = (const float*)d_in[15];
  const float* wob   = (const float*)d_in[16];
  float* ws  = (float*)d_ws;
  float* out = (float*)d_out;

  mla_k1<<<dim3((QLR_ + CE_) / 4), dim3(256), 0, stream>>>(x, wqa, bqa, wkva, bkva, ws);
  mla_k2<<<dim3(1), dim3(256), 0, stream>>>(kvnw, fcos, fsin, ws);
  mla_k3<<<dim3(H_ * (DN_ + DR_) / 8), dim3(256), 0, stream>>>(qnw, wqb, bqb, fcos, fsin, ws);
  mla_k4<<<dim3(16, H_), dim3(256), 0, stream>>>(wkvb, ws);
  mla_k5<<<dim3(NCH_, B_), dim3(512), 0, stream>>>(kvpre, pepre, ws);
  mla_k6<<<dim3(H_, B_), dim3(256), 0, stream>>>(wkvb, ws);
  mla_k7<<<dim3(DIM_ / 4), dim3(256), 0, stream>>>(wo, wob, ws, out);
}